// Round 10
// baseline (5520.174 us; speedup 1.0000x reference)
//
#include <hip/hip_runtime.h>

// ---------------------------------------------------------------------------
// VehicleTrajectoryDecoder: B=32, N=256, D=512, H=8 (dh=64), T=60, DFF=2048.
// R10: R9 confirmed the concurrency model: 2x waves/CU -> 2x fetch rate ->
// 2x speed (FETCH const 1.45GB, 235->477 GB/s). One doubling left: 1024
// threads/block (16 waves/CU, VGPR<=128 via launch_bounds). All phases
// re-sliced for 16 waves (deeper k-splits + LDS partial reduce). Barrier
// discipline: no __syncthreads inside divergent guards (R8 lesson).
// ---------------------------------------------------------------------------

#define NB 32
#define NN 256
#define DD 512
#define NH 8
#define DH 64
#define TT 60
#define DF 2048
#define NBLK 256
#define NTHR 1024

typedef unsigned short ushort_t;

// ---- workspace layout ------------------------------------------------------
constexpr size_t SZ_KV  = (size_t)NB * NN * DD;   // 4194304
constexpr size_t SZ_ROW = (size_t)NB * DD;
constexpr size_t SZ_SAB = (size_t)NB * NH * TT * DH;
constexpr size_t OFF_KS32 = 0;
constexpr size_t OFF_VS32 = SZ_KV;
constexpr size_t OFF_KC32 = 2 * SZ_KV;
constexpr size_t OFF_VC32 = 3 * SZ_KV;
constexpr size_t OFF_X   = 0;
constexpr size_t OFF_ASA = OFF_X   + SZ_ROW;
constexpr size_t OFF_ASP = OFF_ASA + SZ_ROW;
constexpr size_t OFF_ACA = OFF_ASP + SZ_ROW;
constexpr size_t OFF_U1  = OFF_ACA + SZ_ROW;
constexpr size_t OFF_Y1  = OFF_U1  + SZ_ROW;
constexpr size_t OFF_U2  = OFF_Y1  + SZ_ROW;
constexpr size_t OFF_CTX = OFF_U2  + SZ_ROW;
constexpr size_t OFF_U3  = OFF_CTX + SZ_ROW;
constexpr size_t OFF_H   = OFF_U3  + SZ_ROW;
constexpr size_t OFF_BF   = 4 * SZ_KV;
constexpr size_t UOFF_KST = 0;
constexpr size_t UOFF_KCT = SZ_KV;
constexpr size_t UOFF_VSH = 2 * SZ_KV;
constexpr size_t UOFF_VCH = 3 * SZ_KV;
constexpr size_t UOFF_KSA = 4 * SZ_KV;
constexpr size_t UOFF_VSA = UOFF_KSA + SZ_SAB;
constexpr size_t UOFF_W8  = UOFF_VSA + SZ_SAB;
constexpr size_t UOFF_W1  = UOFF_W8 + 8ull * DD * DD;
constexpr size_t UOFF_W2  = UOFF_W1 + (size_t)DD * DF;
constexpr size_t UEND     = UOFF_W2 + (size_t)DF * DD;
constexpr size_t OFF_FLG  = OFF_BF + (UEND + 1) / 2;

// ---- helpers ----------------------------------------------------------------
__device__ __forceinline__ float ldg_a(const float* p) {
  return __hip_atomic_load(p, __ATOMIC_RELAXED, __HIP_MEMORY_SCOPE_AGENT);
}
__device__ __forceinline__ void stg_a(float* p, float v) {
  __hip_atomic_store(p, v, __ATOMIC_RELAXED, __HIP_MEMORY_SCOPE_AGENT);
}
__device__ __forceinline__ float bf2f(ushort_t u) {
  return __uint_as_float(((unsigned)u) << 16);
}
__device__ __forceinline__ ushort_t f2bf(float f) {
  unsigned u = __float_as_uint(f);
  return (ushort_t)((u + 0x7FFFu + ((u >> 16) & 1u)) >> 16);
}

// ---- params ----------------------------------------------------------------
struct Params {
  const float *pe;
  const float *sa_bq, *sa_bk, *sa_bv, *s_bq, *sa_bo, *s_bo, *ca_bq, *ca_bo;
  const float *ln1w, *ln1b, *ln2w, *ln2b, *ln3w, *ln3b;
  const float *b1, *b2, *Wout, *bout;
  const ushort_t *w8, *w1b, *w2b;
  const ushort_t *KsT, *KcT, *VsH, *VcH;
  ushort_t *KsaB, *VsaB;
  float *xcur, *aSA, *aSP, *aCA, *u1, *y1, *u2, *ctx, *u3, *hbuf;
  float *out;
  unsigned *flags, *rels;
};

// ---- grid barrier (R7 proven design) ----------------------------------------
__device__ __forceinline__ void gsync(unsigned* flags, unsigned* rels,
                                      unsigned& round, int tid, int bid) {
  __builtin_amdgcn_s_waitcnt(0);
  __syncthreads();
  round++;
  if (bid == 0) {
    if (tid > 0 && tid < NBLK) {
      while (__hip_atomic_load(&flags[tid], __ATOMIC_RELAXED,
                               __HIP_MEMORY_SCOPE_AGENT) < round)
        __builtin_amdgcn_s_sleep(1);
    }
    __syncthreads();
    if (tid < NBLK)
      __hip_atomic_store(&rels[tid], round, __ATOMIC_RELAXED,
                         __HIP_MEMORY_SCOPE_AGENT);
  } else if (tid == 0) {
    __hip_atomic_store(&flags[bid], round, __ATOMIC_RELAXED,
                       __HIP_MEMORY_SCOPE_AGENT);
    while (__hip_atomic_load(&rels[bid], __ATOMIC_RELAXED,
                             __HIP_MEMORY_SCOPE_AGENT) < round)
      __builtin_amdgcn_s_sleep(1);
  }
  __syncthreads();
}

// ---- persistent decode (256 blocks x 1024 threads, 16 waves/CU) -------------
__global__ __launch_bounds__(1024) void decode_persistent(Params P) {
  __shared__ __align__(16) float sX[2048];     // 8KB
  __shared__ __align__(16) float sPart[1024];  // 4KB k/d-split partials
  __shared__ float sAux[64];
  int tid = threadIdx.x;
  int bid = blockIdx.x;
  unsigned round = 0;

  for (int t = 0; t < TT; t++) {
    // ==== Phase 1: (b,h): proj q/k/v/qs heads + self-attn + spatial =========
    {
      int b = bid >> 3, h = bid & 7;
      if (tid < 512) sX[tid] = ldg_a(P.xcur + (size_t)b * DD + tid);
      __syncthreads();
      {  // proj: wave w: matrix m=w>>2, k-quarter j=w&3; 32 quads each
        int w = tid >> 6, c = tid & 63, m = w >> 2, j = w & 3;
        int col = h * DH + c;
        const ushort4* wp = (const ushort4*)(P.w8 + (size_t)m * DD * DD) + col;
        float acc = 0.f;
        #pragma unroll 8
        for (int kq = j * 32; kq < j * 32 + 32; kq++) {
          ushort4 wv = wp[(size_t)kq * DD];
          float4 xv = *(const float4*)(sX + kq * 4);
          acc += xv.x * bf2f(wv.x) + xv.y * bf2f(wv.y) +
                 xv.z * bf2f(wv.z) + xv.w * bf2f(wv.w);
        }
        sPart[tid] = acc;
      }
      __syncthreads();
      if (tid < 256) {  // combine 4 k-quarters + bias -> sX[512+m*64+c]
        int m = tid >> 6, c = tid & 63, col = h * DH + c;
        const float* bias = (m == 0) ? P.sa_bq : (m == 1) ? P.sa_bk
                          : (m == 2) ? P.sa_bv : P.s_bq;
        float val = sPart[m * 256 + c] + sPart[m * 256 + 64 + c] +
                    sPart[m * 256 + 128 + c] + sPart[m * 256 + 192 + c] + bias[col];
        sX[512 + tid] = val;
        if (m == 1) P.KsaB[((size_t)bid * TT + t) * DH + c] = f2bf(val);
        if (m == 2) P.VsaB[((size_t)bid * TT + t) * DH + c] = f2bf(val);
      }
      __syncthreads();

      // ---- self-attn over L keys (head-private bf16 cache) ----
      int L = t + 1;
      float* sQ  = sX + 512;        // q_self [0,64)
      float* sQs = sX + 512 + 192;  // q_spatial
      float* sPb = sX + 768;        // self probs [64]
      if (tid < 64) {
        float sc = -1e30f;
        if (tid < L) {
          const ushort_t* kp = P.KsaB + ((size_t)bid * TT + tid) * DH;
          float a = 0.f;
          #pragma unroll
          for (int i = 0; i < DH; i += 4) {
            ushort4 kv = *(const ushort4*)(kp + i);
            a += sQ[i] * bf2f(kv.x) + sQ[i + 1] * bf2f(kv.y) +
                 sQ[i + 2] * bf2f(kv.z) + sQ[i + 3] * bf2f(kv.w);
          }
          sc = a * 0.125f;
        }
        float mx = sc;
        #pragma unroll
        for (int s = 32; s >= 1; s >>= 1) mx = fmaxf(mx, __shfl_xor(mx, s));
        float e = (tid < L) ? __expf(sc - mx) : 0.f;
        float s2 = e;
        #pragma unroll
        for (int s = 32; s >= 1; s >>= 1) s2 += __shfl_xor(s2, s);
        sPb[tid] = e;
        if (tid == 0) sAux[12] = 1.f / s2;
      }
      __syncthreads();
      {  // PV: 16 key-groups x 64 d
        int g = tid >> 6, d = tid & 63;
        float a2 = 0.f;
        for (int j = g; j < L; j += 16)
          a2 += sPb[j] * bf2f(P.VsaB[((size_t)bid * TT + j) * DH + d]);
        sPart[tid] = a2;
      }
      __syncthreads();
      if (tid < 64) {
        float o = 0.f;
        #pragma unroll
        for (int i = 0; i < 16; i++) o += sPart[i * 64 + tid];
        stg_a(&P.aSA[(size_t)b * DD + h * DH + tid], o * sAux[12]);
      }
      __syncthreads();

      // ---- spatial attn over 256 keys (4-way d-split scores, 16-way PV) ----
      {
        int n = tid & 255, dq = tid >> 8;  // d-quarter
        const ushort_t* kp = P.KsT + ((size_t)b * DD + h * DH) * NN + n;
        float a = 0.f;
        #pragma unroll 8
        for (int i = dq * 16; i < dq * 16 + 16; i++)
          a += sQs[i] * bf2f(kp[(size_t)i * NN]);
        sPart[tid] = a;
      }
      __syncthreads();
      float* sPr = sX + 1536;  // probs [256]
      if (tid < 256) {  // softmax stage 1 (full-block sync'd)
        float sc = (sPart[tid] + sPart[256 + tid] + sPart[512 + tid] +
                    sPart[768 + tid]) * 0.125f;
        sPr[tid] = sc;
        int w = tid >> 6, lane = tid & 63;
        float mx = sc;
        #pragma unroll
        for (int s = 32; s >= 1; s >>= 1) mx = fmaxf(mx, __shfl_xor(mx, s));
        if (lane == 0) sAux[w] = mx;
      }
      __syncthreads();
      if (tid < 256) {  // softmax stage 2
        int w = tid >> 6, lane = tid & 63;
        float mx = fmaxf(fmaxf(sAux[0], sAux[1]), fmaxf(sAux[2], sAux[3]));
        float e = __expf(sPr[tid] - mx);
        sPr[tid] = e;
        float s2 = e;
        #pragma unroll
        for (int s = 32; s >= 1; s >>= 1) s2 += __shfl_xor(s2, s);
        if (lane == 0) sAux[4 + w] = s2;
      }
      __syncthreads();
      {  // PV: group g of 16 keys, d
        int g = tid >> 6, d = tid & 63;
        float inv = 1.f / (sAux[4] + sAux[5] + sAux[6] + sAux[7]);
        const ushort_t* vp = P.VsH + ((size_t)bid * NN + g * 16) * DH + d;
        float acc = 0.f;
        #pragma unroll 4
        for (int n = 0; n < 16; n++) acc += sPr[g * 16 + n] * bf2f(vp[(size_t)n * DH]);
        sPart[tid] = acc * inv;
      }
      __syncthreads();
      if (tid < 64) {
        float o = 0.f;
        #pragma unroll
        for (int i = 0; i < 16; i++) o += sPart[i * 64 + tid];
        stg_a(&P.aSP[(size_t)b * DD + h * DH + tid], o);
      }
    }
    gsync(P.flags, P.rels, round, tid, bid);

    // ==== Phase 2: u1 = aSA@saWo + sa_bo + x ; ctx = aSP@sWo + s_bo =========
    {
      int s = bid & 7, mz = (bid >> 3) & 1, bg = bid >> 4;  // 2 rows/block
      const float* src = (mz ? P.aSP : P.aSA) + (size_t)bg * 2 * DD;
      sX[tid] = ldg_a(src + tid);  // 1024 floats = 2 rows
      __syncthreads();
      {  // c(64) x r(2) x k8(8): 16 quads each
        int c = tid & 63, r = (tid >> 6) & 1, k8 = tid >> 7, col = s * DH + c;
        const float* xr = sX + r * DD;
        const ushort4* wp = (const ushort4*)(P.w8 + (size_t)(4 + mz) * DD * DD) + col;
        float acc = 0.f;
        #pragma unroll 8
        for (int kq = k8 * 16; kq < k8 * 16 + 16; kq++) {
          ushort4 wv = wp[(size_t)kq * DD];
          float4 xv = *(const float4*)(xr + kq * 4);
          acc += xv.x * bf2f(wv.x) + xv.y * bf2f(wv.y) +
                 xv.z * bf2f(wv.z) + xv.w * bf2f(wv.w);
        }
        sPart[tid] = acc;
      }
      __syncthreads();
      if (tid < 128) {
        int r = tid >> 6, c = tid & 63, col = s * DH + c, b = bg * 2 + r;
        float acc = 0.f;
        #pragma unroll
        for (int j = 0; j < 8; j++) acc += sPart[j * 128 + tid];
        if (mz == 0)
          stg_a(&P.u1[(size_t)b * DD + col],
                acc + P.sa_bo[col] + ldg_a(&P.xcur[(size_t)b * DD + col]));
        else
          stg_a(&P.ctx[(size_t)b * DD + col], acc + P.s_bo[col]);
      }
    }
    gsync(P.flags, P.rels, round, tid, bid);

    // ==== Phase 3: LN1(u1) ; y1(h==0) ; qc head ; cross-attn ================
    {
      int b = bid >> 3, h = bid & 7;
      float v = 0.f;
      if (tid < 512) {
        v = ldg_a(P.u1 + (size_t)b * DD + tid);
        int w = tid >> 6, lane = tid & 63;
        float s = v, q2 = v * v;
        #pragma unroll
        for (int m = 32; m >= 1; m >>= 1) { s += __shfl_xor(s, m); q2 += __shfl_xor(q2, m); }
        if (lane == 0) { sAux[w] = s; sAux[8 + w] = q2; }
      }
      __syncthreads();
      if (tid < 512) {
        float ss = 0.f, qq = 0.f;
        #pragma unroll
        for (int i = 0; i < 8; i++) { ss += sAux[i]; qq += sAux[8 + i]; }
        float mean = ss * (1.f / 512.f);
        float inv = rsqrtf(qq * (1.f / 512.f) - mean * mean + 1e-5f);
        float y = (v - mean) * inv * P.ln1w[tid] + P.ln1b[tid];
        sX[tid] = y;
        if (h == 0) stg_a(&P.y1[(size_t)b * DD + tid], y);
      }
      __syncthreads();
      {  // qc: 16 k-chunks of 8 quads
        int c = tid & 63, w = tid >> 6, col = h * DH + c;
        const ushort4* wp = (const ushort4*)(P.w8 + 6ull * DD * DD) + col;
        float acc = 0.f;
        #pragma unroll 8
        for (int kq = w * 8; kq < w * 8 + 8; kq++) {
          ushort4 wv = wp[(size_t)kq * DD];
          float4 xv = *(const float4*)(sX + kq * 4);
          acc += xv.x * bf2f(wv.x) + xv.y * bf2f(wv.y) +
                 xv.z * bf2f(wv.z) + xv.w * bf2f(wv.w);
        }
        sPart[tid] = acc;
      }
      __syncthreads();
      float* sQc = sX + 512;
      if (tid < 64) {
        float acc = 0.f;
        #pragma unroll
        for (int i = 0; i < 16; i++) acc += sPart[i * 64 + tid];
        sQc[tid] = acc + P.ca_bq[h * DH + tid];
      }
      __syncthreads();
      {  // cross scores (4-way d-split)
        int n = tid & 255, dq = tid >> 8;
        const ushort_t* kp = P.KcT + ((size_t)b * DD + h * DH) * NN + n;
        float a = 0.f;
        #pragma unroll 8
        for (int i = dq * 16; i < dq * 16 + 16; i++)
          a += sQc[i] * bf2f(kp[(size_t)i * NN]);
        sPart[tid] = a;
      }
      __syncthreads();
      float* sPr = sX + 1536;
      if (tid < 256) {
        float sc = (sPart[tid] + sPart[256 + tid] + sPart[512 + tid] +
                    sPart[768 + tid]) * 0.125f;
        sPr[tid] = sc;
        int w = tid >> 6, lane = tid & 63;
        float mx = sc;
        #pragma unroll
        for (int s = 32; s >= 1; s >>= 1) mx = fmaxf(mx, __shfl_xor(mx, s));
        if (lane == 0) sAux[w] = mx;
      }
      __syncthreads();
      if (tid < 256) {
        int w = tid >> 6, lane = tid & 63;
        float mx = fmaxf(fmaxf(sAux[0], sAux[1]), fmaxf(sAux[2], sAux[3]));
        float e = __expf(sPr[tid] - mx);
        sPr[tid] = e;
        float s2 = e;
        #pragma unroll
        for (int s = 32; s >= 1; s >>= 1) s2 += __shfl_xor(s2, s);
        if (lane == 0) sAux[4 + w] = s2;
      }
      __syncthreads();
      {
        int g = tid >> 6, d = tid & 63;
        float inv = 1.f / (sAux[4] + sAux[5] + sAux[6] + sAux[7]);
        const ushort_t* vp = P.VcH + ((size_t)bid * NN + g * 16) * DH + d;
        float acc = 0.f;
        #pragma unroll 4
        for (int n = 0; n < 16; n++) acc += sPr[g * 16 + n] * bf2f(vp[(size_t)n * DH]);
        sPart[tid] = acc * inv;
      }
      __syncthreads();
      if (tid < 64) {
        float o = 0.f;
        #pragma unroll
        for (int i = 0; i < 16; i++) o += sPart[i * 64 + tid];
        stg_a(&P.aCA[(size_t)b * DD + h * DH + tid], o);
      }
    }
    gsync(P.flags, P.rels, round, tid, bid);

    // ==== Phase 4: u2 = aCA@caWo + ca_bo + y1 (128 blocks, 2 rows) ==========
    if (bid < 128) {
      int s = bid & 7, bg = bid >> 3;  // 16 bgroups x 2 rows
      const float* src = P.aCA + (size_t)bg * 2 * DD;
      sX[tid] = ldg_a(src + tid);
      __syncthreads();
      {
        int c = tid & 63, r = (tid >> 6) & 1, k8 = tid >> 7, col = s * DH + c;
        const float* xr = sX + r * DD;
        const ushort4* wp = (const ushort4*)(P.w8 + 7ull * DD * DD) + col;
        float acc = 0.f;
        #pragma unroll 8
        for (int kq = k8 * 16; kq < k8 * 16 + 16; kq++) {
          ushort4 wv = wp[(size_t)kq * DD];
          float4 xv = *(const float4*)(xr + kq * 4);
          acc += xv.x * bf2f(wv.x) + xv.y * bf2f(wv.y) +
                 xv.z * bf2f(wv.z) + xv.w * bf2f(wv.w);
        }
        sPart[tid] = acc;
      }
      __syncthreads();
      if (tid < 128) {
        int r = tid >> 6, c = tid & 63, col = s * DH + c, b = bg * 2 + r;
        float acc = 0.f;
        #pragma unroll
        for (int j = 0; j < 8; j++) acc += sPart[j * 128 + tid];
        stg_a(&P.u2[(size_t)b * DD + col],
              acc + P.ca_bo[col] + ldg_a(&P.y1[(size_t)b * DD + col]));
      }
    }
    gsync(P.flags, P.rels, round, tid, bid);

    // ==== Phase 5: LN2(u2)=z ; u3=z+b2 ; hbuf=relu(z@W1+b1) =================
    {
      int c0 = (bid & 31) * 64, bg = bid >> 5;  // 4 rows, 64 of 2048 cols
      const float* src = P.u2 + (size_t)bg * 4 * DD;
      sX[tid] = ldg_a(src + tid);
      sX[1024 + tid] = ldg_a(src + 1024 + tid);
      __syncthreads();
      {  // LN of 4 rows: wave w -> row w>>2, quarter w&3 (2 elems/lane)
        int w = tid >> 6, lane = tid & 63, r = w >> 2, qr = w & 3;
        float v0 = sX[r * DD + qr * 128 + lane];
        float v1 = sX[r * DD + qr * 128 + lane + 64];
        float s = v0 + v1, q2 = v0 * v0 + v1 * v1;
        #pragma unroll
        for (int m = 32; m >= 1; m >>= 1) { s += __shfl_xor(s, m); q2 += __shfl_xor(q2, m); }
        if (lane == 0) { sAux[w] = s; sAux[16 + w] = q2; }
      }
      __syncthreads();
      #pragma unroll
      for (int i = 0; i < 2; i++) {
        int idx = i * 1024 + tid, r = idx >> 9, col = idx & 511;
        float mean = (sAux[r * 4] + sAux[r * 4 + 1] + sAux[r * 4 + 2] +
                      sAux[r * 4 + 3]) * (1.f / 512.f);
        float inv = rsqrtf((sAux[16 + r * 4] + sAux[16 + r * 4 + 1] +
                            sAux[16 + r * 4 + 2] + sAux[16 + r * 4 + 3]) *
                           (1.f / 512.f) - mean * mean + 1e-5f);
        sX[idx] = (sX[idx] - mean) * inv * P.ln2w[col] + P.ln2b[col];
      }
      __syncthreads();
      if ((bid & 31) == 0) {
        #pragma unroll
        for (int i = 0; i < 2; i++) {
          int idx = i * 1024 + tid, r = idx >> 9, col = idx & 511;
          stg_a(&P.u3[(size_t)(bg * 4 + r) * DD + col], sX[idx] + P.b2[col]);
        }
      }
      {  // FFN1: c(64) x r(4) x k4(4): 32 quads each
        int c = tid & 63, r = (tid >> 6) & 3, k4 = tid >> 8, col = c0 + c;
        const float* xr = sX + r * DD;
        const ushort4* wp = (const ushort4*)P.w1b + col;
        float acc = 0.f;
        #pragma unroll 8
        for (int kq = k4 * 32; kq < k4 * 32 + 32; kq++) {
          ushort4 wv = wp[(size_t)kq * DF];
          float4 xv = *(const float4*)(xr + kq * 4);
          acc += xv.x * bf2f(wv.x) + xv.y * bf2f(wv.y) +
                 xv.z * bf2f(wv.z) + xv.w * bf2f(wv.w);
        }
        sPart[tid] = acc;
      }
      __syncthreads();
      if (tid < 256) {
        int r = tid >> 6, c = tid & 63, col = c0 + c, b = bg * 4 + r;
        float acc = sPart[tid] + sPart[256 + tid] + sPart[512 + tid] + sPart[768 + tid];
        stg_a(&P.hbuf[(size_t)b * DF + col], fmaxf(acc + P.b1[col], 0.f));
      }
    }
    gsync(P.flags, P.rels, round, tid, bid);

    // ==== Phase 6: u3 += hbuf@W2 (split-k x4, atomics) ======================
    {
      int s = bid & 7, ks = (bid >> 3) & 3, bg = bid >> 5;
      int k0 = ks * 512;
      #pragma unroll
      for (int i = 0; i < 2; i++) {
        int f = i * 1024 + tid, r = f >> 9, cc = f & 511;
        sX[f] = ldg_a(&P.hbuf[(size_t)(bg * 4 + r) * DF + k0 + cc]);
      }
      __syncthreads();
      {
        int c = tid & 63, r = (tid >> 6) & 3, k4 = tid >> 8, col = s * DH + c;
        const float* xr = sX + r * DD;
        const ushort4* wp = (const ushort4*)P.w2b + (size_t)(k0 >> 2) * DD + col;
        float acc = 0.f;
        #pragma unroll 8
        for (int kq = k4 * 32; kq < k4 * 32 + 32; kq++) {
          ushort4 wv = wp[(size_t)kq * DD];
          float4 xv = *(const float4*)(xr + kq * 4);
          acc += xv.x * bf2f(wv.x) + xv.y * bf2f(wv.y) +
                 xv.z * bf2f(wv.z) + xv.w * bf2f(wv.w);
        }
        sPart[tid] = acc;
      }
      __syncthreads();
      if (tid < 256) {
        int r = tid >> 6, c = tid & 63, col = s * DH + c, b = bg * 4 + r;
        atomicAdd(&P.u3[(size_t)b * DD + col],
                  sPart[tid] + sPart[256 + tid] + sPart[512 + tid] + sPart[768 + tid]);
      }
    }
    gsync(P.flags, P.rels, round, tid, bid);

    // ==== Phase 7: nxt = LN3(u3)+ctx ; out ; xcur = nxt + pe[t+1] ===========
    if (bid < NB) {
      int b = bid;
      float u = 0.f;
      if (tid < 512) {
        u = ldg_a(&P.u3[(size_t)b * DD + tid]);
        int w = tid >> 6, lane = tid & 63;
        float s = u, q2 = u * u;
        #pragma unroll
        for (int m = 32; m >= 1; m >>= 1) { s += __shfl_xor(s, m); q2 += __shfl_xor(q2, m); }
        if (lane == 0) { sAux[w] = s; sAux[8 + w] = q2; }
      }
      __syncthreads();
      if (tid < 512) {
        float ss = 0.f, qq = 0.f;
        #pragma unroll
        for (int i = 0; i < 8; i++) { ss += sAux[i]; qq += sAux[8 + i]; }
        float mean = ss * (1.f / 512.f);
        float inv = rsqrtf(qq * (1.f / 512.f) - mean * mean + 1e-5f);
        float nxt = (u - mean) * inv * P.ln3w[tid] + P.ln3b[tid] +
                    ldg_a(&P.ctx[(size_t)b * DD + tid]);
        sX[tid] = nxt;
        float p = (t < TT - 1) ? P.pe[(size_t)(t + 1) * DD + tid] : 0.f;
        stg_a(&P.xcur[(size_t)b * DD + tid], nxt + p);
      }
      __syncthreads();
      {  // out proj: c = tid>>9, one element per thread, 16-wave reduce
        int c = tid >> 9, l = tid & 511;
        float a = sX[l] * P.Wout[(size_t)c * DD + l];
        #pragma unroll
        for (int m = 32; m >= 1; m >>= 1) a += __shfl_xor(a, m);
        if ((tid & 63) == 0) sAux[16 + (tid >> 6)] = a;
      }
      __syncthreads();
      if (tid == 0) {
        float a = 0.f;
        #pragma unroll
        for (int i = 0; i < 8; i++) a += sAux[16 + i];
        P.out[((size_t)b * TT + t) * 2 + 0] = a + P.bout[0];
      }
      if (tid == 512) {
        float a = 0.f;
        #pragma unroll
        for (int i = 0; i < 8; i++) a += sAux[24 + i];
        P.out[((size_t)b * TT + t) * 2 + 1] = a + P.bout[1];
      }
    }
    gsync(P.flags, P.rels, round, tid, bid);
  }
}

// ---- precompute kernels (unchanged from R7) ---------------------------------
__global__ __launch_bounds__(256) void gemm_kv(
    const float* __restrict__ A,
    const float* __restrict__ W0, const float* __restrict__ W1_,
    const float* __restrict__ W2_, const float* __restrict__ W3_,
    const float* __restrict__ b0, const float* __restrict__ b1_,
    const float* __restrict__ b2_, const float* __restrict__ b3_,
    float* __restrict__ O0, float* __restrict__ O1,
    float* __restrict__ O2, float* __restrict__ O3) {
  __shared__ __align__(16) float As[8][128];
  __shared__ __align__(16) float Bs[8][128];
  int tid = threadIdx.x;
  int bx = blockIdx.x, by = blockIdx.y;
  int mm = bx >> 2;
  int col0 = (bx & 3) * 128;
  const float* W = mm == 0 ? W0 : mm == 1 ? W1_ : mm == 2 ? W2_ : W3_;
  const float* bias = mm == 0 ? b0 : mm == 1 ? b1_ : mm == 2 ? b2_ : b3_;
  float* O = mm == 0 ? O0 : mm == 1 ? O1 : mm == 2 ? O2 : O3;
  int tx = tid & 15, ty = tid >> 4;
  int m0 = by * 128;
  int lr = tid >> 1, lk = (tid & 1) * 4;
  const float* Ap = A + (size_t)(m0 + lr) * DD + lk;
  const float* Wp = W + (size_t)(col0 + lr) * DD + lk;
  float c[8][8] = {};
  for (int k0 = 0; k0 < DD; k0 += 8) {
    float4 av = *(const float4*)(Ap + k0);
    float4 wv = *(const float4*)(Wp + k0);
    __syncthreads();
    As[lk + 0][lr] = av.x; As[lk + 1][lr] = av.y; As[lk + 2][lr] = av.z; As[lk + 3][lr] = av.w;
    Bs[lk + 0][lr] = wv.x; Bs[lk + 1][lr] = wv.y; Bs[lk + 2][lr] = wv.z; Bs[lk + 3][lr] = wv.w;
    __syncthreads();
    #pragma unroll
    for (int k = 0; k < 8; k++) {
      float a[8], bb[8];
      *(float4*)&a[0] = *(const float4*)&As[k][ty * 8];
      *(float4*)&a[4] = *(const float4*)&As[k][ty * 8 + 4];
      *(float4*)&bb[0] = *(const float4*)&Bs[k][tx * 8];
      *(float4*)&bb[4] = *(const float4*)&Bs[k][tx * 8 + 4];
      #pragma unroll
      for (int i = 0; i < 8; i++)
        #pragma unroll
        for (int j = 0; j < 8; j++) c[i][j] += a[i] * bb[j];
    }
  }
  const float* bp = bias + col0 + tx * 8;
  for (int i = 0; i < 8; i++) {
    int row = m0 + ty * 8 + i;
    float* op = O + (size_t)row * DD + col0 + tx * 8;
    #pragma unroll
    for (int jq = 0; jq < 8; jq += 4) {
      float4 v;
      v.x = c[i][jq + 0] + bp[jq + 0];
      v.y = c[i][jq + 1] + bp[jq + 1];
      v.z = c[i][jq + 2] + bp[jq + 2];
      v.w = c[i][jq + 3] + bp[jq + 3];
      *(float4*)(op + jq) = v;
    }
  }
}

__global__ __launch_bounds__(256) void pack_kT(const float* __restrict__ Ks32,
                                               const float* __restrict__ Kc32,
                                               ushort_t* __restrict__ KsT,
                                               ushort_t* __restrict__ KcT) {
  int z = blockIdx.z;
  int b = z >> 1;
  const float* in = ((z & 1) ? Kc32 : Ks32) + (size_t)b * NN * DD;
  ushort_t* out = ((z & 1) ? KcT : KsT) + (size_t)b * NN * DD;
  int r0 = blockIdx.x * 32, c0 = blockIdx.y * 32;
  __shared__ float tile[32][33];
  int tid = threadIdx.x;
  int i = tid >> 3, j4 = (tid & 7) * 4;
  float4 v = *(const float4*)(in + (size_t)(r0 + i) * DD + c0 + j4);
  tile[i][j4] = v.x; tile[i][j4 + 1] = v.y; tile[i][j4 + 2] = v.z; tile[i][j4 + 3] = v.w;
  __syncthreads();
  ushort_t* op = out + (size_t)(c0 + i) * NN + r0 + j4;
  op[0] = f2bf(tile[j4][i]); op[1] = f2bf(tile[j4 + 1][i]);
  op[2] = f2bf(tile[j4 + 2][i]); op[3] = f2bf(tile[j4 + 3][i]);
}

__global__ __launch_bounds__(256) void pack_vh(const float* __restrict__ Vs32,
                                               const float* __restrict__ Vc32,
                                               ushort_t* __restrict__ VsH,
                                               ushort_t* __restrict__ VcH) {
  const float* src = blockIdx.y ? Vc32 : Vs32;
  ushort_t* dst = blockIdx.y ? VcH : VsH;
  size_t idx = (size_t)blockIdx.x * 1024 + threadIdx.x * 4;
  float4 v = *(const float4*)(src + idx);
  int d512 = (int)(idx & 511);
  int n = (int)((idx >> 9) & 255);
  int b = (int)(idx >> 17);
  int h = d512 >> 6, d = d512 & 63;
  ushort_t* op = dst + (((size_t)(b * 8 + h) * NN + n) * DH + d);
  op[0] = f2bf(v.x); op[1] = f2bf(v.y); op[2] = f2bf(v.z); op[3] = f2bf(v.w);
}

struct PWItem { const float* in; ushort_t* out; int C; int K; };
struct PWArgs { PWItem m[10]; };
__global__ __launch_bounds__(256) void pack_w(PWArgs a) {
  PWItem it = a.m[blockIdx.y];
  int total = it.C * (it.K >> 2);
  int e = blockIdx.x * 256 + threadIdx.x;
  if (e >= total) return;
  int kd = it.K >> 2;
  int k4 = e % kd, col = e / kd;
  float4 v = *(const float4*)(it.in + (size_t)col * it.K + k4 * 4);
  ushort4 o;
  o.x = f2bf(v.x); o.y = f2bf(v.y); o.z = f2bf(v.z); o.w = f2bf(v.w);
  *((ushort4*)it.out + (size_t)k4 * it.C + col) = o;
}

__global__ __launch_bounds__(256) void init_x(const float* __restrict__ hv0,
                                              const float* __restrict__ pe,
                                              float* __restrict__ xcur,
                                              unsigned* __restrict__ flags) {
  int i = blockIdx.x * 256 + threadIdx.x;
  xcur[i] = hv0[i] + pe[i & (DD - 1)];
  if (i < 1024) flags[i] = 0u;
}

// ---------------------------------------------------------------------------
extern "C" void kernel_launch(void* const* d_in, const int* in_sizes, int n_in,
                              void* d_out, int out_size, void* d_ws, size_t ws_size,
                              hipStream_t stream) {
  const float* H_v_all = (const float*)d_in[0];
  const float* H_v0    = (const float*)d_in[1];
  const float* pe      = (const float*)d_in[2];
  const float* s_Wq = (const float*)d_in[3];
  const float* s_Wk = (const float*)d_in[4];
  const float* s_Wv = (const float*)d_in[5];
  const float* s_Wo = (const float*)d_in[6];
  const float* s_bq = (const float*)d_in[7];
  const float* s_bk = (const float*)d_in[8];
  const float* s_bv = (const float*)d_in[9];
  const float* s_bo = (const float*)d_in[10];
  const float* sa_Wq = (const float*)d_in[11];
  const float* sa_Wk = (const float*)d_in[12];
  const float* sa_Wv = (const float*)d_in[13];
  const float* sa_Wo = (const float*)d_in[14];
  const float* sa_bq = (const float*)d_in[15];
  const float* sa_bk = (const float*)d_in[16];
  const float* sa_bv = (const float*)d_in[17];
  const float* sa_bo = (const float*)d_in[18];
  const float* ca_Wq = (const float*)d_in[19];
  const float* ca_Wk = (const float*)d_in[20];
  const float* ca_Wv = (const float*)d_in[21];
  const float* ca_Wo = (const float*)d_in[22];
  const float* ca_bq = (const float*)d_in[23];
  const float* ca_bk = (const float*)d_in[24];
  const float* ca_bv = (const float*)d_in[25];
  const float* ca_bo = (const float*)d_in[26];
  const float* ln1w = (const float*)d_in[27];
  const float* ln1b = (const float*)d_in[28];
  const float* ln2w = (const float*)d_in[29];
  const float* ln2b = (const float*)d_in[30];
  const float* ln3w = (const float*)d_in[31];
  const float* ln3b = (const float*)d_in[32];
  const float* W1   = (const float*)d_in[33];
  const float* b1   = (const float*)d_in[34];
  const float* W2   = (const float*)d_in[35];
  const float* b2   = (const float*)d_in[36];
  const float* Wout = (const float*)d_in[37];
  const float* bout = (const float*)d_in[38];

  float* ws = (float*)d_ws;
  float* Ks32 = ws + OFF_KS32;
  float* Vs32 = ws + OFF_VS32;
  float* Kc32 = ws + OFF_KC32;
  float* Vc32 = ws + OFF_VC32;
  ushort_t* ub = (ushort_t*)(ws + OFF_BF);
  unsigned* flags = (unsigned*)(ws + OFF_FLG);

  hipLaunchKernelGGL(gemm_kv, dim3(16, 64), dim3(256), 0, stream,
                     H_v_all, s_Wk, s_Wv, ca_Wk, ca_Wv,
                     s_bk, s_bv, ca_bk, ca_bv, Ks32, Vs32, Kc32, Vc32);

  hipLaunchKernelGGL(pack_kT, dim3(8, 16, 64), dim3(256), 0, stream,
                     Ks32, Kc32, ub + UOFF_KST, ub + UOFF_KCT);
  hipLaunchKernelGGL(pack_vh, dim3((unsigned)(SZ_KV / 1024), 2), dim3(256), 0,
                     stream, Vs32, Vc32, ub + UOFF_VSH, ub + UOFF_VCH);

  PWArgs pw;
  pw.m[0] = {sa_Wq, ub + UOFF_W8 + 0ull * DD * DD, DD, DD};
  pw.m[1] = {sa_Wk, ub + UOFF_W8 + 1ull * DD * DD, DD, DD};
  pw.m[2] = {sa_Wv, ub + UOFF_W8 + 2ull * DD * DD, DD, DD};
  pw.m[3] = {s_Wq,  ub + UOFF_W8 + 3ull * DD * DD, DD, DD};
  pw.m[4] = {sa_Wo, ub + UOFF_W8 + 4ull * DD * DD, DD, DD};
  pw.m[5] = {s_Wo,  ub + UOFF_W8 + 5ull * DD * DD, DD, DD};
  pw.m[6] = {ca_Wq, ub + UOFF_W8 + 6ull * DD * DD, DD, DD};
  pw.m[7] = {ca_Wo, ub + UOFF_W8 + 7ull * DD * DD, DD, DD};
  pw.m[8] = {W1, ub + UOFF_W1, DF, DD};
  pw.m[9] = {W2, ub + UOFF_W2, DD, DF};
  hipLaunchKernelGGL(pack_w, dim3(1024, 10), dim3(256), 0, stream, pw);

  hipLaunchKernelGGL(init_x, dim3(64), dim3(256), 0, stream,
                     H_v0, pe, ws + OFF_X, flags);

  Params P;
  P.pe = pe;
  P.sa_bq = sa_bq; P.sa_bk = sa_bk; P.sa_bv = sa_bv; P.s_bq = s_bq;
  P.sa_bo = sa_bo; P.s_bo = s_bo; P.ca_bq = ca_bq; P.ca_bo = ca_bo;
  P.ln1w = ln1w; P.ln1b = ln1b; P.ln2w = ln2w; P.ln2b = ln2b;
  P.ln3w = ln3w; P.ln3b = ln3b;
  P.b1 = b1; P.b2 = b2; P.Wout = Wout; P.bout = bout;
  P.w8 = ub + UOFF_W8; P.w1b = ub + UOFF_W1; P.w2b = ub + UOFF_W2;
  P.KsT = ub + UOFF_KST; P.KcT = ub + UOFF_KCT;
  P.VsH = ub + UOFF_VSH; P.VcH = ub + UOFF_VCH;
  P.KsaB = ub + UOFF_KSA; P.VsaB = ub + UOFF_VSA;
  P.xcur = ws + OFF_X;
  P.aSA = ws + OFF_ASA; P.aSP = ws + OFF_ASP; P.aCA = ws + OFF_ACA;
  P.u1 = ws + OFF_U1; P.y1 = ws + OFF_Y1; P.u2 = ws + OFF_U2;
  P.ctx = ws + OFF_CTX; P.u3 = ws + OFF_U3; P.hbuf = ws + OFF_H;
  P.out = (float*)d_out;
  P.flags = flags;
  P.rels = flags + 512;

  void* kargs[] = { (void*)&P };
  hipLaunchCooperativeKernel((void*)decode_persistent, dim3(NBLK), dim3(NTHR),
                             kargs, 0, stream);
}